// Round 1
// baseline (1042.769 us; speedup 1.0000x reference)
//
#include <hip/hip_runtime.h>
#include <math.h>

#define TOTAL_ANCHORS 87296
#define NSEL 4256
#define NWORDS 67          // ceil(4256/64)
#define NREP 32            // histogram replicas
#define CHUNK 16           // sweep prefetch depth

// ---------- helpers ----------
__device__ __forceinline__ float sigmoidf_(float x) {
    return 1.0f / (1.0f + expf(-x));
}
// monotone float->uint mapping (ascending)
__device__ __forceinline__ unsigned int f2s(float f) {
    unsigned int u = __float_as_uint(f);
    return u ^ ((u >> 31) ? 0xFFFFFFFFu : 0x80000000u);
}
__device__ __forceinline__ unsigned long long shfl64(unsigned long long v, int src) {
    unsigned int lo = (unsigned int)(v & 0xFFFFFFFFull);
    unsigned int hi = (unsigned int)(v >> 32);
    lo = (unsigned int)__shfl((int)lo, src, 64);
    hi = (unsigned int)__shfl((int)hi, src, 64);
    return ((unsigned long long)hi << 32) | (unsigned long long)lo;
}

struct InPtrs {
    const float* cls[5];
    const float* reg[5];
    const float* ctn[5];
    const float* scales;
};

// ---------- 1. decode: per-anchor score/label/box + sort key ----------
__global__ __launch_bounds__(256) void decode_kernel(InPtrs in,
        unsigned long long* __restrict__ keys, float* __restrict__ scores,
        int* __restrict__ labels, float4* __restrict__ boxes) {
    int g = blockIdx.x * 256 + threadIdx.x;
    if (g >= TOTAL_ANCHORS) return;
    int lv, base, W, stride;
    if (g < 65536)      { lv = 0; base = 0;     W = 256; stride = 8;   }
    else if (g < 81920) { lv = 1; base = 65536; W = 128; stride = 16;  }
    else if (g < 86016) { lv = 2; base = 81920; W = 64;  stride = 32;  }
    else if (g < 87040) { lv = 3; base = 86016; W = 32;  stride = 64;  }
    else                { lv = 4; base = 87040; W = 16;  stride = 128; }
    int p = g - base;
    int HW = W * W;
    int x = p & (W - 1);
    int y = p / W;
    const float* cls = in.cls[lv];
    float sctn = sigmoidf_(in.ctn[lv][p]);
    float best = -1.0f; int lbl = 0;
    for (int c = 0; c < 80; ++c) {
        float v = cls[c * HW + p];
        float pr = sqrtf(__fmul_rn(sigmoidf_(v), sctn));
        if (pr > best) { best = pr; lbl = c; }   // strict > : first-index argmax
    }
    float scale = in.scales[lv];
    float fs = (float)stride;
    const float* rg = in.reg[lv];
    float r0 = __fmul_rn(fmaxf(__fmul_rn(rg[0 * HW + p], scale), 0.0f), fs);
    float r1 = __fmul_rn(fmaxf(__fmul_rn(rg[1 * HW + p], scale), 0.0f), fs);
    float r2 = __fmul_rn(fmaxf(__fmul_rn(rg[2 * HW + p], scale), 0.0f), fs);
    float r3 = __fmul_rn(fmaxf(__fmul_rn(rg[3 * HW + p], scale), 0.0f), fs);
    float ax = __fmul_rn(__fadd_rn((float)x, 0.5f), fs);
    float ay = __fmul_rn(__fadd_rn((float)y, 0.5f), fs);
    float4 b;
    b.x = __fsub_rn(ax, r0);
    b.y = __fsub_rn(ay, r1);
    b.z = __fadd_rn(ax, r2);
    b.w = __fadd_rn(ay, r3);
    scores[g] = best;
    labels[g] = lbl;
    boxes[g]  = b;
    // key: score desc, local index asc on ties (lax.top_k semantics)
    keys[g] = ((unsigned long long)f2s(best) << 32) | (unsigned int)(~(unsigned int)p);
}

// ---------- 2. per-level top-1000 (radix-select + bitonic), one block/level ----------
__global__ __launch_bounds__(1024) void topk_kernel(
        const unsigned long long* __restrict__ keys,
        unsigned long long* __restrict__ sel) {
    __shared__ unsigned int hist[NREP][256];
    __shared__ unsigned int histm[256];
    __shared__ unsigned long long sh_prefix;
    __shared__ int sh_need;
    __shared__ unsigned long long skeys[1024];
    __shared__ int cnt;
    const int level = blockIdx.x;
    const int Ns_[4]   = {65536, 16384, 4096, 1024};
    const int offs_[4] = {0, 65536, 81920, 86016};
    const int N = Ns_[level];
    const unsigned long long* kbase = keys + offs_[level];
    const int tid = threadIdx.x;
    const int rep = tid & (NREP - 1);
    unsigned long long prefix = 0ull;
    int need = 1000;
    for (int bp = 7; bp >= 0; --bp) {
        for (int i = tid; i < NREP * 256; i += 1024) ((unsigned int*)hist)[i] = 0u;
        __syncthreads();
        const int shift = bp * 8;
        for (int i = tid; i < N; i += 1024) {
            unsigned long long k = kbase[i];
            unsigned long long hi = k >> shift;
            if ((hi >> 8) == prefix) atomicAdd(&hist[rep][(int)(hi & 255ull)], 1u);
        }
        __syncthreads();
        if (tid < 256) {
            unsigned int s = 0;
            for (int r2 = 0; r2 < NREP; ++r2) s += hist[r2][tid];
            histm[tid] = s;
        }
        __syncthreads();
        if (tid == 0) {
            int c = 0, b = 255;
            for (; b >= 0; --b) { int h = (int)histm[b]; if (c + h >= need) break; c += h; }
            if (b < 0) b = 0;
            sh_prefix = (prefix << 8) | (unsigned long long)(unsigned int)b;
            sh_need = need - c;
        }
        __syncthreads();
        prefix = sh_prefix;
        need = sh_need;
        __syncthreads();
    }
    // prefix == exact 1000th-largest key (keys unique) -> exactly 1000 keys >= prefix
    if (tid == 0) cnt = 0;
    skeys[tid] = 0ull;
    __syncthreads();
    for (int i = tid; i < N; i += 1024) {
        unsigned long long k = kbase[i];
        if (k >= prefix) { int p = atomicAdd(&cnt, 1); if (p < 1024) skeys[p] = k; }
    }
    __syncthreads();
    // bitonic sort 1024 descending
    for (int kk = 2; kk <= 1024; kk <<= 1) {
        for (int j = kk >> 1; j > 0; j >>= 1) {
            int ixj = tid ^ j;
            if (ixj > tid) {
                unsigned long long a = skeys[tid], b2 = skeys[ixj];
                bool sw = ((tid & kk) == 0) ? (a < b2) : (a > b2);
                if (sw) { skeys[tid] = b2; skeys[ixj] = a; }
            }
            __syncthreads();
        }
    }
    if (tid < 1000) sel[level * 1000 + tid] = skeys[tid];
}

// ---------- 3. finalize: gather selected, write outputs, build NMS entries ----------
__global__ __launch_bounds__(256) void finalize_kernel(
        const unsigned long long* __restrict__ sel,
        const float* __restrict__ scores, const int* __restrict__ labels,
        const float4* __restrict__ boxes, float* __restrict__ out,
        float4* __restrict__ entbox, float* __restrict__ entarea,
        int* __restrict__ entvalid, unsigned long long* __restrict__ entkey) {
    int pos = blockIdx.x * 256 + threadIdx.x;
    if (pos >= NSEL) return;
    int g;
    if (pos < 4000) {
        int lv = pos / 1000;
        const int offs_[4] = {0, 65536, 81920, 86016};
        unsigned long long key = sel[pos];
        unsigned int p = ~((unsigned int)(key & 0xFFFFFFFFull));
        g = offs_[lv] + (int)p;
    } else {
        g = 87040 + (pos - 4000);   // level 4: raw order
    }
    float sc = scores[g];
    int lb = labels[g];
    float4 bx = boxes[g];
    const float inv = 1.0f / 2048.0f;   // /2048 == *2^-11 exactly
    out[pos * 4 + 0] = fminf(fmaxf(__fmul_rn(bx.x, inv), 0.0f), 1.0f);
    out[pos * 4 + 1] = fminf(fmaxf(__fmul_rn(bx.y, inv), 0.0f), 1.0f);
    out[pos * 4 + 2] = fminf(fmaxf(__fmul_rn(bx.z, inv), 0.0f), 1.0f);
    out[pos * 4 + 3] = fminf(fmaxf(__fmul_rn(bx.w, inv), 0.0f), 1.0f);
    out[17024 + pos] = sc;
    out[21280 + pos] = (float)lb;
    out[25536 + pos] = 0.0f;            // keep: default false, sweep sets kept=1
    float off = __fmul_rn((float)lb, 100000.0f);
    float x1 = __fadd_rn(bx.x, off), y1 = __fadd_rn(bx.y, off);
    float x2 = __fadd_rn(bx.z, off), y2 = __fadd_rn(bx.w, off);
    float4 eb; eb.x = x1; eb.y = y1; eb.z = x2; eb.w = y2;
    entbox[pos] = eb;
    entarea[pos] = __fmul_rn(__fsub_rn(x2, x1), __fsub_rn(y2, y1));
    int valid = (sc >= 0.05f) ? 1 : 0;
    entvalid[pos] = valid;
    float effs = valid ? sc : -INFINITY;  // matches where(valid, s, -inf); suffix-monotone per chunk
    entkey[pos] = ((unsigned long long)f2s(effs) << 32) | (unsigned int)(~(unsigned int)pos);
}

// ---------- 4. sort the 256 level-4 entries (only unsorted chunk) ----------
__global__ __launch_bounds__(256) void sortl4_kernel(
        const unsigned long long* __restrict__ entkey,
        unsigned long long* __restrict__ skey4) {
    __shared__ unsigned long long sk[256];
    int tid = threadIdx.x;
    sk[tid] = entkey[4000 + tid];
    __syncthreads();
    for (int kk = 2; kk <= 256; kk <<= 1) {
        for (int j = kk >> 1; j > 0; j >>= 1) {
            int ixj = tid ^ j;
            if (ixj > tid) {
                unsigned long long a = sk[tid], b = sk[ixj];
                bool sw = ((tid & kk) == 0) ? (a < b) : (a > b);
                if (sw) { sk[tid] = b; sk[ixj] = a; }
            }
            __syncthreads();
        }
    }
    skey4[tid] = sk[tid];
}

// ---------- 5. merge-rank: global stable sort via binary-search ranks ----------
__device__ __forceinline__ int count_greater(const unsigned long long* A, int n,
                                             unsigned long long x) {
    int lo = 0, hi = n;
    while (lo < hi) { int m = (lo + hi) >> 1; if (A[m] > x) lo = m + 1; else hi = m; }
    return lo;
}
__global__ __launch_bounds__(256) void mergerank_kernel(
        const unsigned long long* __restrict__ entkey,
        const unsigned long long* __restrict__ skey4,
        const float4* __restrict__ entbox, const float* __restrict__ entarea,
        const int* __restrict__ entvalid,
        int* __restrict__ order, float4* __restrict__ sbox,
        float* __restrict__ sarea, int* __restrict__ svalid) {
    int pos = blockIdx.x * 256 + threadIdx.x;
    if (pos >= NSEL) return;
    unsigned long long x = entkey[pos];
    int rank = count_greater(entkey,        1000, x)
             + count_greater(entkey + 1000, 1000, x)
             + count_greater(entkey + 2000, 1000, x)
             + count_greater(entkey + 3000, 1000, x)
             + count_greater(skey4,          256, x);
    order[rank]  = pos;
    sbox[rank]   = entbox[pos];
    sarea[rank]  = entarea[pos];
    svalid[rank] = entvalid[pos];
}

// ---------- 6. IoU bitmask (sorted order), 64x64 tiles ----------
__global__ __launch_bounds__(64) void mask_kernel(
        const float4* __restrict__ sbox, const float* __restrict__ sarea,
        unsigned long long* __restrict__ mask) {
    __shared__ float4 cb[64];
    __shared__ float ca[64];
    int tid = threadIdx.x;
    int colTile = blockIdx.x, rowTile = blockIdx.y;
    int col0 = colTile * 64;
    int c = col0 + tid;
    if (c < NSEL) { cb[tid] = sbox[c]; ca[tid] = sarea[c]; }
    else { cb[tid] = make_float4(0.f, 0.f, 0.f, 0.f); ca[tid] = 0.f; }
    __syncthreads();
    int i = rowTile * 64 + tid;
    if (i < NSEL) {
        float4 b = sbox[i];
        float ar = sarea[i];
        unsigned long long bits = 0ull;
        int jmax = min(64, NSEL - col0);
        for (int j = 0; j < jmax; ++j) {
            float xx1 = fmaxf(b.x, cb[j].x);
            float yy1 = fmaxf(b.y, cb[j].y);
            float xx2 = fminf(b.z, cb[j].z);
            float yy2 = fminf(b.w, cb[j].w);
            float w = fmaxf(1e-10f, __fsub_rn(xx2, xx1));
            float h = fmaxf(1e-10f, __fsub_rn(yy2, yy1));
            float inter = __fmul_rn(w, h);
            float denom = __fadd_rn(__fsub_rn(__fadd_rn(ar, ca[j]), inter), 1e-14f);
            float ovr = __fdiv_rn(inter, denom);
            if (ovr > 0.6f) bits |= (1ull << j);
        }
        mask[(size_t)i * NWORDS + colTile] = bits;
    }
}

// ---------- 7. serial greedy sweep (single wave, register-prefetched rows) ----------
__global__ __launch_bounds__(64) void sweep_kernel(
        const unsigned long long* __restrict__ mask,
        const int* __restrict__ order, const int* __restrict__ svalid,
        float* __restrict__ out_keep) {
    int lane = threadIdx.x;
    __shared__ int sval[NSEL];
    __shared__ int sord[NSEL];
    for (int i = lane; i < NSEL; i += 64) { sval[i] = svalid[i]; sord[i] = order[i]; }
    __syncthreads();
    unsigned long long remv0 = 0ull, remv1 = 0ull;
    unsigned long long bufA[CHUNK], bufA2[CHUNK], bufB[CHUNK], bufB2[CHUNK];
    const int NCH = NSEL / CHUNK;   // 266, exact

    auto prefetch = [&](unsigned long long (&b0)[CHUNK], unsigned long long (&b1)[CHUNK],
                        int base) {
        #pragma unroll
        for (int r = 0; r < CHUNK; ++r) {
            int i = base + r;
            if (i < NSEL) {
                b0[r] = mask[(size_t)i * NWORDS + lane];
                b1[r] = (lane < 3) ? mask[(size_t)i * NWORDS + 64 + lane] : 0ull;
            } else { b0[r] = 0ull; b1[r] = 0ull; }
        }
    };
    auto process = [&](unsigned long long (&b0)[CHUNK], unsigned long long (&b1)[CHUNK],
                       int base) {
        #pragma unroll
        for (int r = 0; r < CHUNK; ++r) {
            int i = base + r;
            int w = i >> 6, b = i & 63;
            int ws_ = (w < 64) ? w : (w - 64);
            unsigned long long rw = (w < 64) ? shfl64(remv0, ws_) : shfl64(remv1, ws_);
            bool kept = (sval[i] != 0) && (((rw >> b) & 1ull) == 0ull);
            if (kept) {
                remv0 |= b0[r];
                remv1 |= b1[r];
                if (lane == 0) out_keep[sord[i]] = 1.0f;
            }
        }
    };

    prefetch(bufA, bufA2, 0);
    for (int c = 0; c < NCH; c += 2) {
        prefetch(bufB, bufB2, (c + 1) * CHUNK);
        process(bufA, bufA2, c * CHUNK);
        prefetch(bufA, bufA2, (c + 2) * CHUNK);
        process(bufB, bufB2, (c + 1) * CHUNK);
    }
}

// ---------- workspace layout (all 16B-aligned) ----------
constexpr size_t OFF_KEYS    = 0;                            // u64 * 87296
constexpr size_t OFF_SCORES  = OFF_KEYS    + 698368;         // f32 * 87296
constexpr size_t OFF_LABELS  = OFF_SCORES  + 349184;         // i32 * 87296
constexpr size_t OFF_BOXES   = OFF_LABELS  + 349184;         // f32x4 * 87296
constexpr size_t OFF_SEL     = OFF_BOXES   + 1396736;        // u64 * 4000
constexpr size_t OFF_ENTBOX  = OFF_SEL     + 32000;          // f32x4 * 4256
constexpr size_t OFF_ENTAREA = OFF_ENTBOX  + 68096;          // f32 * 4256
constexpr size_t OFF_ENTVAL  = OFF_ENTAREA + 17024;          // i32 * 4256
constexpr size_t OFF_ENTKEY  = OFF_ENTVAL  + 17024;          // u64 * 4256
constexpr size_t OFF_SKEY4   = OFF_ENTKEY  + 34048;          // u64 * 256
constexpr size_t OFF_ORDER   = OFF_SKEY4   + 2048;           // i32 * 4256
constexpr size_t OFF_SBOX    = OFF_ORDER   + 17024;          // f32x4 * 4256
constexpr size_t OFF_SAREA   = OFF_SBOX    + 68096;          // f32 * 4256
constexpr size_t OFF_SVALID  = OFF_SAREA   + 17024;          // i32 * 4256
constexpr size_t OFF_MASK    = OFF_SVALID  + 17024;          // u64 * 4256 * 67

extern "C" void kernel_launch(void* const* d_in, const int* in_sizes, int n_in,
                              void* d_out, int out_size, void* d_ws, size_t ws_size,
                              hipStream_t stream) {
    (void)in_sizes; (void)n_in; (void)out_size; (void)ws_size;
    InPtrs P;
    for (int lv = 0; lv < 5; ++lv) {
        P.cls[lv] = (const float*)d_in[3 * lv + 0];
        P.reg[lv] = (const float*)d_in[3 * lv + 1];
        P.ctn[lv] = (const float*)d_in[3 * lv + 2];
    }
    P.scales = (const float*)d_in[15];

    char* ws = (char*)d_ws;
    unsigned long long* keys   = (unsigned long long*)(ws + OFF_KEYS);
    float*              scores = (float*)             (ws + OFF_SCORES);
    int*                labels = (int*)               (ws + OFF_LABELS);
    float4*             boxes  = (float4*)            (ws + OFF_BOXES);
    unsigned long long* sel    = (unsigned long long*)(ws + OFF_SEL);
    float4*             entbox = (float4*)            (ws + OFF_ENTBOX);
    float*              entarea= (float*)             (ws + OFF_ENTAREA);
    int*                entval = (int*)               (ws + OFF_ENTVAL);
    unsigned long long* entkey = (unsigned long long*)(ws + OFF_ENTKEY);
    unsigned long long* skey4  = (unsigned long long*)(ws + OFF_SKEY4);
    int*                order  = (int*)               (ws + OFF_ORDER);
    float4*             sbox   = (float4*)            (ws + OFF_SBOX);
    float*              sarea  = (float*)             (ws + OFF_SAREA);
    int*                svalid = (int*)               (ws + OFF_SVALID);
    unsigned long long* maskb  = (unsigned long long*)(ws + OFF_MASK);
    float* out = (float*)d_out;

    decode_kernel<<<TOTAL_ANCHORS / 256, 256, 0, stream>>>(P, keys, scores, labels, boxes);
    topk_kernel<<<4, 1024, 0, stream>>>(keys, sel);
    finalize_kernel<<<(NSEL + 255) / 256, 256, 0, stream>>>(sel, scores, labels, boxes,
                                                            out, entbox, entarea, entval, entkey);
    sortl4_kernel<<<1, 256, 0, stream>>>(entkey, skey4);
    mergerank_kernel<<<(NSEL + 255) / 256, 256, 0, stream>>>(entkey, skey4, entbox, entarea,
                                                             entval, order, sbox, sarea, svalid);
    mask_kernel<<<dim3(NWORDS, NWORDS), 64, 0, stream>>>(sbox, sarea, maskb);
    sweep_kernel<<<1, 64, 0, stream>>>(maskb, order, svalid, out + 25536);
}

// Round 2
// 563.842 us; speedup vs baseline: 1.8494x; 1.8494x over previous
//
#include <hip/hip_runtime.h>
#include <math.h>

#define TOTAL_ANCHORS 87296
#define NSEL 4256
#define NWORDS 67          // ceil(4256/64)
#define NPAD   4288        // 67*64, padded row count for word-major mask
#define NREP 32            // histogram replicas

// ---------- helpers ----------
__device__ __forceinline__ float sigmoidf_(float x) {
    return 1.0f / (1.0f + expf(-x));
}
// monotone float->uint mapping (ascending)
__device__ __forceinline__ unsigned int f2s(float f) {
    unsigned int u = __float_as_uint(f);
    return u ^ ((u >> 31) ? 0xFFFFFFFFu : 0x80000000u);
}

struct InPtrs {
    const float* cls[5];
    const float* reg[5];
    const float* ctn[5];
    const float* scales;
};

// ---------- 1. decode: per-anchor score/label/box + sort key ----------
__global__ __launch_bounds__(256) void decode_kernel(InPtrs in,
        unsigned long long* __restrict__ keys, float* __restrict__ scores,
        int* __restrict__ labels, float4* __restrict__ boxes) {
    int g = blockIdx.x * 256 + threadIdx.x;
    if (g >= TOTAL_ANCHORS) return;
    int lv, base, W, stride;
    if (g < 65536)      { lv = 0; base = 0;     W = 256; stride = 8;   }
    else if (g < 81920) { lv = 1; base = 65536; W = 128; stride = 16;  }
    else if (g < 86016) { lv = 2; base = 81920; W = 64;  stride = 32;  }
    else if (g < 87040) { lv = 3; base = 86016; W = 32;  stride = 64;  }
    else                { lv = 4; base = 87040; W = 16;  stride = 128; }
    int p = g - base;
    int HW = W * W;
    int x = p & (W - 1);
    int y = p / W;
    const float* cls = in.cls[lv];
    float sctn = sigmoidf_(in.ctn[lv][p]);
    float best = -1.0f; int lbl = 0;
    for (int c = 0; c < 80; ++c) {
        float v = cls[c * HW + p];
        float pr = sqrtf(__fmul_rn(sigmoidf_(v), sctn));
        if (pr > best) { best = pr; lbl = c; }   // strict > : first-index argmax
    }
    float scale = in.scales[lv];
    float fs = (float)stride;
    const float* rg = in.reg[lv];
    float r0 = __fmul_rn(fmaxf(__fmul_rn(rg[0 * HW + p], scale), 0.0f), fs);
    float r1 = __fmul_rn(fmaxf(__fmul_rn(rg[1 * HW + p], scale), 0.0f), fs);
    float r2 = __fmul_rn(fmaxf(__fmul_rn(rg[2 * HW + p], scale), 0.0f), fs);
    float r3 = __fmul_rn(fmaxf(__fmul_rn(rg[3 * HW + p], scale), 0.0f), fs);
    float ax = __fmul_rn(__fadd_rn((float)x, 0.5f), fs);
    float ay = __fmul_rn(__fadd_rn((float)y, 0.5f), fs);
    float4 b;
    b.x = __fsub_rn(ax, r0);
    b.y = __fsub_rn(ay, r1);
    b.z = __fadd_rn(ax, r2);
    b.w = __fadd_rn(ay, r3);
    scores[g] = best;
    labels[g] = lbl;
    boxes[g]  = b;
    // key: score desc, local index asc on ties (lax.top_k semantics)
    keys[g] = ((unsigned long long)f2s(best) << 32) | (unsigned int)(~(unsigned int)p);
}

// ---------- 2. per-level top-1000 (radix-select + bitonic), one block/level ----------
__global__ __launch_bounds__(1024) void topk_kernel(
        const unsigned long long* __restrict__ keys,
        unsigned long long* __restrict__ sel) {
    __shared__ unsigned int hist[NREP][256];
    __shared__ unsigned int histm[256];
    __shared__ unsigned long long sh_prefix;
    __shared__ int sh_need;
    __shared__ unsigned long long skeys[1024];
    __shared__ int cnt;
    const int level = blockIdx.x;
    const int Ns_[4]   = {65536, 16384, 4096, 1024};
    const int offs_[4] = {0, 65536, 81920, 86016};
    const int N = Ns_[level];
    const unsigned long long* kbase = keys + offs_[level];
    const int tid = threadIdx.x;
    const int rep = tid & (NREP - 1);
    unsigned long long prefix = 0ull;
    int need = 1000;
    for (int bp = 7; bp >= 0; --bp) {
        for (int i = tid; i < NREP * 256; i += 1024) ((unsigned int*)hist)[i] = 0u;
        __syncthreads();
        const int shift = bp * 8;
        for (int i = tid; i < N; i += 1024) {
            unsigned long long k = kbase[i];
            unsigned long long hi = k >> shift;
            if ((hi >> 8) == prefix) atomicAdd(&hist[rep][(int)(hi & 255ull)], 1u);
        }
        __syncthreads();
        if (tid < 256) {
            unsigned int s = 0;
            for (int r2 = 0; r2 < NREP; ++r2) s += hist[r2][tid];
            histm[tid] = s;
        }
        __syncthreads();
        if (tid == 0) {
            int c = 0, b = 255;
            for (; b >= 0; --b) { int h = (int)histm[b]; if (c + h >= need) break; c += h; }
            if (b < 0) b = 0;
            sh_prefix = (prefix << 8) | (unsigned long long)(unsigned int)b;
            sh_need = need - c;
        }
        __syncthreads();
        prefix = sh_prefix;
        need = sh_need;
        __syncthreads();
    }
    // prefix == exact 1000th-largest key (keys unique) -> exactly 1000 keys >= prefix
    if (tid == 0) cnt = 0;
    skeys[tid] = 0ull;
    __syncthreads();
    for (int i = tid; i < N; i += 1024) {
        unsigned long long k = kbase[i];
        if (k >= prefix) { int p = atomicAdd(&cnt, 1); if (p < 1024) skeys[p] = k; }
    }
    __syncthreads();
    // bitonic sort 1024 descending
    for (int kk = 2; kk <= 1024; kk <<= 1) {
        for (int j = kk >> 1; j > 0; j >>= 1) {
            int ixj = tid ^ j;
            if (ixj > tid) {
                unsigned long long a = skeys[tid], b2 = skeys[ixj];
                bool sw = ((tid & kk) == 0) ? (a < b2) : (a > b2);
                if (sw) { skeys[tid] = b2; skeys[ixj] = a; }
            }
            __syncthreads();
        }
    }
    if (tid < 1000) sel[level * 1000 + tid] = skeys[tid];
}

// ---------- 3. finalize: gather selected, write outputs, build NMS entries ----------
__global__ __launch_bounds__(256) void finalize_kernel(
        const unsigned long long* __restrict__ sel,
        const float* __restrict__ scores, const int* __restrict__ labels,
        const float4* __restrict__ boxes, float* __restrict__ out,
        float4* __restrict__ entbox, float* __restrict__ entarea,
        int* __restrict__ entvalid, unsigned long long* __restrict__ entkey) {
    int pos = blockIdx.x * 256 + threadIdx.x;
    if (pos >= NSEL) return;
    int g;
    if (pos < 4000) {
        int lv = pos / 1000;
        const int offs_[4] = {0, 65536, 81920, 86016};
        unsigned long long key = sel[pos];
        unsigned int p = ~((unsigned int)(key & 0xFFFFFFFFull));
        g = offs_[lv] + (int)p;
    } else {
        g = 87040 + (pos - 4000);   // level 4: raw order
    }
    float sc = scores[g];
    int lb = labels[g];
    float4 bx = boxes[g];
    const float inv = 1.0f / 2048.0f;   // /2048 == *2^-11 exactly
    out[pos * 4 + 0] = fminf(fmaxf(__fmul_rn(bx.x, inv), 0.0f), 1.0f);
    out[pos * 4 + 1] = fminf(fmaxf(__fmul_rn(bx.y, inv), 0.0f), 1.0f);
    out[pos * 4 + 2] = fminf(fmaxf(__fmul_rn(bx.z, inv), 0.0f), 1.0f);
    out[pos * 4 + 3] = fminf(fmaxf(__fmul_rn(bx.w, inv), 0.0f), 1.0f);
    out[17024 + pos] = sc;
    out[21280 + pos] = (float)lb;
    out[25536 + pos] = 0.0f;            // keep: default false, sweep sets kept=1
    float off = __fmul_rn((float)lb, 100000.0f);
    float x1 = __fadd_rn(bx.x, off), y1 = __fadd_rn(bx.y, off);
    float x2 = __fadd_rn(bx.z, off), y2 = __fadd_rn(bx.w, off);
    float4 eb; eb.x = x1; eb.y = y1; eb.z = x2; eb.w = y2;
    entbox[pos] = eb;
    entarea[pos] = __fmul_rn(__fsub_rn(x2, x1), __fsub_rn(y2, y1));
    int valid = (sc >= 0.05f) ? 1 : 0;
    entvalid[pos] = valid;
    float effs = valid ? sc : -INFINITY;  // matches where(valid, s, -inf); suffix-monotone per chunk
    entkey[pos] = ((unsigned long long)f2s(effs) << 32) | (unsigned int)(~(unsigned int)pos);
}

// ---------- 4. sort the 256 level-4 entries (only unsorted chunk) ----------
__global__ __launch_bounds__(256) void sortl4_kernel(
        const unsigned long long* __restrict__ entkey,
        unsigned long long* __restrict__ skey4) {
    __shared__ unsigned long long sk[256];
    int tid = threadIdx.x;
    sk[tid] = entkey[4000 + tid];
    __syncthreads();
    for (int kk = 2; kk <= 256; kk <<= 1) {
        for (int j = kk >> 1; j > 0; j >>= 1) {
            int ixj = tid ^ j;
            if (ixj > tid) {
                unsigned long long a = sk[tid], b = sk[ixj];
                bool sw = ((tid & kk) == 0) ? (a < b) : (a > b);
                if (sw) { sk[tid] = b; sk[ixj] = a; }
            }
            __syncthreads();
        }
    }
    skey4[tid] = sk[tid];
}

// ---------- 5. merge-rank: global stable sort via binary-search ranks ----------
__device__ __forceinline__ int count_greater(const unsigned long long* A, int n,
                                             unsigned long long x) {
    int lo = 0, hi = n;
    while (lo < hi) { int m = (lo + hi) >> 1; if (A[m] > x) lo = m + 1; else hi = m; }
    return lo;
}
__global__ __launch_bounds__(256) void mergerank_kernel(
        const unsigned long long* __restrict__ entkey,
        const unsigned long long* __restrict__ skey4,
        const float4* __restrict__ entbox, const float* __restrict__ entarea,
        const int* __restrict__ entvalid,
        int* __restrict__ order, float4* __restrict__ sbox,
        float* __restrict__ sarea, int* __restrict__ svalid) {
    int pos = blockIdx.x * 256 + threadIdx.x;
    if (pos >= NSEL) return;
    unsigned long long x = entkey[pos];
    int rank = count_greater(entkey,        1000, x)
             + count_greater(entkey + 1000, 1000, x)
             + count_greater(entkey + 2000, 1000, x)
             + count_greater(entkey + 3000, 1000, x)
             + count_greater(skey4,          256, x);
    order[rank]  = pos;
    sbox[rank]   = entbox[pos];
    sarea[rank]  = entarea[pos];
    svalid[rank] = entvalid[pos];
}

// ---------- 6. IoU bitmask, WORD-MAJOR layout: maskC[w*NPAD + row] ----------
// Only lower-triangle word tiles (colTile <= rowTile) are ever read by the sweep.
__global__ __launch_bounds__(64) void mask_kernel(
        const float4* __restrict__ sbox, const float* __restrict__ sarea,
        unsigned long long* __restrict__ maskC) {
    int colTile = blockIdx.x, rowTile = blockIdx.y;
    if (colTile > rowTile) return;
    __shared__ float4 cb[64];
    __shared__ float ca[64];
    int tid = threadIdx.x;
    int col0 = colTile * 64;
    int c = col0 + tid;
    if (c < NSEL) { cb[tid] = sbox[c]; ca[tid] = sarea[c]; }
    else { cb[tid] = make_float4(0.f, 0.f, 0.f, 0.f); ca[tid] = 0.f; }
    __syncthreads();
    int i = rowTile * 64 + tid;
    unsigned long long bits = 0ull;
    if (i < NSEL) {
        float4 b = sbox[i];
        float ar = sarea[i];
        for (int j = 0; j < 64; ++j) {
            float xx1 = fmaxf(b.x, cb[j].x);
            float yy1 = fmaxf(b.y, cb[j].y);
            float xx2 = fminf(b.z, cb[j].z);
            float yy2 = fminf(b.w, cb[j].w);
            float w = fmaxf(1e-10f, __fsub_rn(xx2, xx1));
            float h = fmaxf(1e-10f, __fsub_rn(yy2, yy1));
            float inter = __fmul_rn(w, h);
            float denom = __fadd_rn(__fsub_rn(__fadd_rn(ar, ca[j]), inter), 1e-14f);
            float ovr = __fdiv_rn(inter, denom);
            if (ovr > 0.6f) bits |= (1ull << j);
        }
        // bits for pad columns (c>=NSEL) are garbage-by-construction but never used
    }
    maskC[(size_t)colTile * NPAD + i] = bits;   // coalesced across tid
}

// ---------- 7. greedy sweep: block-serial, zero memory ops in the serial chain ----
// Symmetry: mask[i][j] == mask[j][i], so row c's bits are also column c's
// suppressor bits. Per 64-row block:
//   (a) parallel: sup_c = OR_{w<b} (maskC[w][c] & keptw[w])   (coalesced loads)
//   (b) ballot -> avail (wave-uniform), diag word per lane
//   (c) serial 64 iters, pure SALU/readlane: if avail bit r: K|=bit; avail &= ~row_r
__global__ __launch_bounds__(64) void sweep_kernel(
        const unsigned long long* __restrict__ maskC,
        const int* __restrict__ order, const int* __restrict__ svalid,
        float* __restrict__ out_keep) {
    int lane = threadIdx.x;
    __shared__ int sval[NSEL];
    __shared__ int sord[NSEL];
    __shared__ unsigned long long keptw[NWORDS];
    for (int i = lane; i < NSEL; i += 64) { sval[i] = svalid[i]; sord[i] = order[i]; }
    __syncthreads();
    for (int b = 0; b < NWORDS; ++b) {
        int c = b * 64 + lane;                 // this lane's row (c < NPAD always)
        bool inb = (c < NSEL);
        // (a) suppression by kept rows of earlier blocks
        unsigned long long acc = 0ull;
        #pragma unroll 4
        for (int w = 0; w < b; ++w) {
            acc |= (maskC[(size_t)w * NPAD + c] & keptw[w]);
        }
        unsigned long long diag = maskC[(size_t)b * NPAD + c];
        bool alive = inb && (sval[c] != 0) && (acc == 0ull);
        unsigned long long avail = __ballot(alive);
        // (c) serial intra-block sweep — uniform registers only
        unsigned long long K = 0ull;
        #pragma unroll
        for (int r = 0; r < 64; ++r) {
            if (avail & (1ull << r)) {
                K |= (1ull << r);
                unsigned int rl = __builtin_amdgcn_readlane((unsigned int)(diag & 0xFFFFFFFFull), r);
                unsigned int rh = __builtin_amdgcn_readlane((unsigned int)(diag >> 32), r);
                avail &= ~(((unsigned long long)rh << 32) | (unsigned long long)rl);
            }
        }
        if (inb && ((K >> lane) & 1ull)) out_keep[sord[c]] = 1.0f;
        if (lane == 0) keptw[b] = K;
        __syncthreads();   // publish keptw[b] to all lanes before next block reads it
    }
}

// ---------- workspace layout (all 16B-aligned) ----------
constexpr size_t OFF_KEYS    = 0;                            // u64 * 87296
constexpr size_t OFF_SCORES  = OFF_KEYS    + 698368;         // f32 * 87296
constexpr size_t OFF_LABELS  = OFF_SCORES  + 349184;         // i32 * 87296
constexpr size_t OFF_BOXES   = OFF_LABELS  + 349184;         // f32x4 * 87296
constexpr size_t OFF_SEL     = OFF_BOXES   + 1396736;        // u64 * 4000
constexpr size_t OFF_ENTBOX  = OFF_SEL     + 32000;          // f32x4 * 4256
constexpr size_t OFF_ENTAREA = OFF_ENTBOX  + 68096;          // f32 * 4256
constexpr size_t OFF_ENTVAL  = OFF_ENTAREA + 17024;          // i32 * 4256
constexpr size_t OFF_ENTKEY  = OFF_ENTVAL  + 17024;          // u64 * 4256
constexpr size_t OFF_SKEY4   = OFF_ENTKEY  + 34048;          // u64 * 256
constexpr size_t OFF_ORDER   = OFF_SKEY4   + 2048;           // i32 * 4256
constexpr size_t OFF_SBOX    = OFF_ORDER   + 17024;          // f32x4 * 4256
constexpr size_t OFF_SAREA   = OFF_SBOX    + 68096;          // f32 * 4256
constexpr size_t OFF_SVALID  = OFF_SAREA   + 17024;          // i32 * 4256
constexpr size_t OFF_MASK    = OFF_SVALID  + 17024;          // u64 * NWORDS * NPAD

extern "C" void kernel_launch(void* const* d_in, const int* in_sizes, int n_in,
                              void* d_out, int out_size, void* d_ws, size_t ws_size,
                              hipStream_t stream) {
    (void)in_sizes; (void)n_in; (void)out_size; (void)ws_size;
    InPtrs P;
    for (int lv = 0; lv < 5; ++lv) {
        P.cls[lv] = (const float*)d_in[3 * lv + 0];
        P.reg[lv] = (const float*)d_in[3 * lv + 1];
        P.ctn[lv] = (const float*)d_in[3 * lv + 2];
    }
    P.scales = (const float*)d_in[15];

    char* ws = (char*)d_ws;
    unsigned long long* keys   = (unsigned long long*)(ws + OFF_KEYS);
    float*              scores = (float*)             (ws + OFF_SCORES);
    int*                labels = (int*)               (ws + OFF_LABELS);
    float4*             boxes  = (float4*)            (ws + OFF_BOXES);
    unsigned long long* sel    = (unsigned long long*)(ws + OFF_SEL);
    float4*             entbox = (float4*)            (ws + OFF_ENTBOX);
    float*              entarea= (float*)             (ws + OFF_ENTAREA);
    int*                entval = (int*)               (ws + OFF_ENTVAL);
    unsigned long long* entkey = (unsigned long long*)(ws + OFF_ENTKEY);
    unsigned long long* skey4  = (unsigned long long*)(ws + OFF_SKEY4);
    int*                order  = (int*)               (ws + OFF_ORDER);
    float4*             sbox   = (float4*)            (ws + OFF_SBOX);
    float*              sarea  = (float*)             (ws + OFF_SAREA);
    int*                svalid = (int*)               (ws + OFF_SVALID);
    unsigned long long* maskb  = (unsigned long long*)(ws + OFF_MASK);
    float* out = (float*)d_out;

    decode_kernel<<<TOTAL_ANCHORS / 256, 256, 0, stream>>>(P, keys, scores, labels, boxes);
    topk_kernel<<<4, 1024, 0, stream>>>(keys, sel);
    finalize_kernel<<<(NSEL + 255) / 256, 256, 0, stream>>>(sel, scores, labels, boxes,
                                                            out, entbox, entarea, entval, entkey);
    sortl4_kernel<<<1, 256, 0, stream>>>(entkey, skey4);
    mergerank_kernel<<<(NSEL + 255) / 256, 256, 0, stream>>>(entkey, skey4, entbox, entarea,
                                                             entval, order, sbox, sarea, svalid);
    mask_kernel<<<dim3(NWORDS, NWORDS), 64, 0, stream>>>(sbox, sarea, maskb);
    sweep_kernel<<<1, 64, 0, stream>>>(maskb, order, svalid, out + 25536);
}

// Round 3
// 443.887 us; speedup vs baseline: 2.3492x; 1.2702x over previous
//
#include <hip/hip_runtime.h>
#include <math.h>

#define TOTAL_ANCHORS 87296
#define NSEL 4256
#define NWORDS 67          // ceil(4256/64)
#define NPAD   4288        // 67*64, padded row count for word-major mask
#define NREP 32            // histogram replicas

// ---------- helpers ----------
__device__ __forceinline__ float sigmoidf_(float x) {
    return 1.0f / (1.0f + expf(-x));
}
// monotone float->uint mapping (ascending)
__device__ __forceinline__ unsigned int f2s(float f) {
    unsigned int u = __float_as_uint(f);
    return u ^ ((u >> 31) ? 0xFFFFFFFFu : 0x80000000u);
}

struct InPtrs {
    const float* cls[5];
    const float* reg[5];
    const float* ctn[5];
    const float* scales;
};

// ---------- 1. decode: per-anchor score/label/box + sort key ----------
__global__ __launch_bounds__(256) void decode_kernel(InPtrs in,
        unsigned long long* __restrict__ keys, float* __restrict__ scores,
        int* __restrict__ labels, float4* __restrict__ boxes) {
    int g = blockIdx.x * 256 + threadIdx.x;
    if (g >= TOTAL_ANCHORS) return;
    int lv, base, W, stride;
    if (g < 65536)      { lv = 0; base = 0;     W = 256; stride = 8;   }
    else if (g < 81920) { lv = 1; base = 65536; W = 128; stride = 16;  }
    else if (g < 86016) { lv = 2; base = 81920; W = 64;  stride = 32;  }
    else if (g < 87040) { lv = 3; base = 86016; W = 32;  stride = 64;  }
    else                { lv = 4; base = 87040; W = 16;  stride = 128; }
    int p = g - base;
    int HW = W * W;
    int x = p & (W - 1);
    int y = p / W;
    const float* cls = in.cls[lv];
    float sctn = sigmoidf_(in.ctn[lv][p]);
    float best = -1.0f; int lbl = 0;
    for (int c = 0; c < 80; ++c) {
        float v = cls[c * HW + p];
        float pr = sqrtf(__fmul_rn(sigmoidf_(v), sctn));
        if (pr > best) { best = pr; lbl = c; }   // strict > : first-index argmax
    }
    float scale = in.scales[lv];
    float fs = (float)stride;
    const float* rg = in.reg[lv];
    float r0 = __fmul_rn(fmaxf(__fmul_rn(rg[0 * HW + p], scale), 0.0f), fs);
    float r1 = __fmul_rn(fmaxf(__fmul_rn(rg[1 * HW + p], scale), 0.0f), fs);
    float r2 = __fmul_rn(fmaxf(__fmul_rn(rg[2 * HW + p], scale), 0.0f), fs);
    float r3 = __fmul_rn(fmaxf(__fmul_rn(rg[3 * HW + p], scale), 0.0f), fs);
    float ax = __fmul_rn(__fadd_rn((float)x, 0.5f), fs);
    float ay = __fmul_rn(__fadd_rn((float)y, 0.5f), fs);
    float4 b;
    b.x = __fsub_rn(ax, r0);
    b.y = __fsub_rn(ay, r1);
    b.z = __fadd_rn(ax, r2);
    b.w = __fadd_rn(ay, r3);
    scores[g] = best;
    labels[g] = lbl;
    boxes[g]  = b;
    // key: score desc, local index asc on ties (lax.top_k semantics)
    keys[g] = ((unsigned long long)f2s(best) << 32) | (unsigned int)(~(unsigned int)p);
}

// ---------- 2. per-level top-1000 (radix-select + bitonic), one block/level ----------
// hist layout [bin][rep]: LDS bank = (bin*NREP + rep) & 31 = rep -> conflict-free
// regardless of digit concentration (the old [rep][bin] layout put every lane
// with the same digit in the same bank).
__global__ __launch_bounds__(1024) void topk_kernel(
        const unsigned long long* __restrict__ keys,
        unsigned long long* __restrict__ sel) {
    __shared__ unsigned int hist[256][NREP];
    __shared__ unsigned int histm[256];
    __shared__ unsigned long long sh_prefix;
    __shared__ int sh_need;
    __shared__ unsigned long long skeys[1024];
    __shared__ int cnt;
    const int level = blockIdx.x;
    const int Ns_[4]   = {65536, 16384, 4096, 1024};
    const int offs_[4] = {0, 65536, 81920, 86016};
    const int N = Ns_[level];
    const unsigned long long* kbase = keys + offs_[level];
    const int tid = threadIdx.x;
    const int rep = tid & (NREP - 1);
    unsigned long long prefix = 0ull;
    int need = 1000;
    for (int bp = 7; bp >= 0; --bp) {
        for (int i = tid; i < 256 * NREP; i += 1024) ((unsigned int*)hist)[i] = 0u;
        __syncthreads();
        const int shift = bp * 8;
        for (int i = tid; i < N; i += 1024) {
            unsigned long long k = kbase[i];
            unsigned long long hi = k >> shift;
            if ((hi >> 8) == prefix) atomicAdd(&hist[(int)(hi & 255ull)][rep], 1u);
        }
        __syncthreads();
        if (tid < 256) {
            unsigned int s = 0;
            #pragma unroll
            for (int r2 = 0; r2 < NREP; ++r2) s += hist[tid][(r2 + tid) & (NREP - 1)];
            histm[tid] = s;
        }
        __syncthreads();
        if (tid == 0) {
            int c = 0, b = 255;
            for (; b >= 0; --b) { int h = (int)histm[b]; if (c + h >= need) break; c += h; }
            if (b < 0) b = 0;
            sh_prefix = (prefix << 8) | (unsigned long long)(unsigned int)b;
            sh_need = need - c;
        }
        __syncthreads();
        prefix = sh_prefix;
        need = sh_need;
        __syncthreads();
    }
    // prefix == exact 1000th-largest key (keys unique) -> exactly 1000 keys >= prefix
    if (tid == 0) cnt = 0;
    skeys[tid] = 0ull;
    __syncthreads();
    for (int i = tid; i < N; i += 1024) {
        unsigned long long k = kbase[i];
        if (k >= prefix) { int p = atomicAdd(&cnt, 1); if (p < 1024) skeys[p] = k; }
    }
    __syncthreads();
    // bitonic sort 1024 descending
    for (int kk = 2; kk <= 1024; kk <<= 1) {
        for (int j = kk >> 1; j > 0; j >>= 1) {
            int ixj = tid ^ j;
            if (ixj > tid) {
                unsigned long long a = skeys[tid], b2 = skeys[ixj];
                bool sw = ((tid & kk) == 0) ? (a < b2) : (a > b2);
                if (sw) { skeys[tid] = b2; skeys[ixj] = a; }
            }
            __syncthreads();
        }
    }
    if (tid < 1000) sel[level * 1000 + tid] = skeys[tid];
}

// ---------- 3. fused mid: finalize + sort-l4 + merge-rank (one block, 1024 thr) ----
__device__ __forceinline__ int count_greater(const unsigned long long* A, int n,
                                             unsigned long long x) {
    int lo = 0, hi = n;
    while (lo < hi) { int m = (lo + hi) >> 1; if (A[m] > x) lo = m + 1; else hi = m; }
    return lo;
}
__global__ __launch_bounds__(1024) void mid_kernel(
        const unsigned long long* __restrict__ sel,
        const float* __restrict__ scores, const int* __restrict__ labels,
        const float4* __restrict__ boxes, float* __restrict__ out,
        int* __restrict__ order, float4* __restrict__ sbox,
        float* __restrict__ sarea, int* __restrict__ svalid) {
    __shared__ unsigned long long ekey[NSEL];
    __shared__ unsigned long long sk4[256];
    const int tid = threadIdx.x;
    float4 bxs[5]; float ars[5]; int vls[5];
    // ---- phase 1: finalize (gather top-k, write outputs, build NMS entries) ----
    #pragma unroll
    for (int k = 0; k < 5; ++k) {
        int pos = tid + k * 1024;
        if (pos < NSEL) {
            int g;
            if (pos < 4000) {
                int lv = pos / 1000;
                const int offs_[4] = {0, 65536, 81920, 86016};
                unsigned long long key = sel[pos];
                unsigned int p = ~((unsigned int)(key & 0xFFFFFFFFull));
                g = offs_[lv] + (int)p;
            } else {
                g = 87040 + (pos - 4000);   // level 4: raw order
            }
            float sc = scores[g];
            int lb = labels[g];
            float4 bx = boxes[g];
            const float inv = 1.0f / 2048.0f;   // /2048 == *2^-11 exactly
            out[pos * 4 + 0] = fminf(fmaxf(__fmul_rn(bx.x, inv), 0.0f), 1.0f);
            out[pos * 4 + 1] = fminf(fmaxf(__fmul_rn(bx.y, inv), 0.0f), 1.0f);
            out[pos * 4 + 2] = fminf(fmaxf(__fmul_rn(bx.z, inv), 0.0f), 1.0f);
            out[pos * 4 + 3] = fminf(fmaxf(__fmul_rn(bx.w, inv), 0.0f), 1.0f);
            out[17024 + pos] = sc;
            out[21280 + pos] = (float)lb;
            out[25536 + pos] = 0.0f;            // keep default; sweep sets kept=1
            float off = __fmul_rn((float)lb, 100000.0f);
            float4 eb;
            eb.x = __fadd_rn(bx.x, off); eb.y = __fadd_rn(bx.y, off);
            eb.z = __fadd_rn(bx.z, off); eb.w = __fadd_rn(bx.w, off);
            bxs[k] = eb;
            ars[k] = __fmul_rn(__fsub_rn(eb.z, eb.x), __fsub_rn(eb.w, eb.y));
            int valid = (sc >= 0.05f) ? 1 : 0;
            vls[k] = valid;
            float effs = valid ? sc : -INFINITY;
            ekey[pos] = ((unsigned long long)f2s(effs) << 32) | (unsigned int)(~(unsigned int)pos);
        }
    }
    __syncthreads();
    // ---- phase 2: bitonic-sort the 256 level-4 keys (only unsorted chunk) ----
    if (tid < 256) sk4[tid] = ekey[4000 + tid];
    __syncthreads();
    for (int kk = 2; kk <= 256; kk <<= 1) {
        for (int j = kk >> 1; j > 0; j >>= 1) {
            if (tid < 256) {
                int ixj = tid ^ j;
                if (ixj > tid) {
                    unsigned long long a = sk4[tid], b = sk4[ixj];
                    bool sw = ((tid & kk) == 0) ? (a < b) : (a > b);
                    if (sw) { sk4[tid] = b; sk4[ixj] = a; }
                }
            }
            __syncthreads();
        }
    }
    // ---- phase 3: merge-rank (stable global sort via binary-search ranks) ----
    #pragma unroll
    for (int k = 0; k < 5; ++k) {
        int pos = tid + k * 1024;
        if (pos < NSEL) {
            unsigned long long x = ekey[pos];
            int rank = count_greater(ekey,        1000, x)
                     + count_greater(ekey + 1000, 1000, x)
                     + count_greater(ekey + 2000, 1000, x)
                     + count_greater(ekey + 3000, 1000, x)
                     + count_greater(sk4,          256, x);
            order[rank]  = pos;
            sbox[rank]   = bxs[k];
            sarea[rank]  = ars[k];
            svalid[rank] = vls[k];
        }
    }
}

// ---------- 4. IoU bitmask, WORD-MAJOR layout: maskC[w*NPAD + row] ----------
// Only lower-triangle word tiles (colTile <= rowTile) are ever read by the sweep.
__global__ __launch_bounds__(64) void mask_kernel(
        const float4* __restrict__ sbox, const float* __restrict__ sarea,
        unsigned long long* __restrict__ maskC) {
    int colTile = blockIdx.x, rowTile = blockIdx.y;
    if (colTile > rowTile) return;
    __shared__ float4 cb[64];
    __shared__ float ca[64];
    int tid = threadIdx.x;
    int col0 = colTile * 64;
    int c = col0 + tid;
    if (c < NSEL) { cb[tid] = sbox[c]; ca[tid] = sarea[c]; }
    else { cb[tid] = make_float4(0.f, 0.f, 0.f, 0.f); ca[tid] = 0.f; }
    __syncthreads();
    int i = rowTile * 64 + tid;
    unsigned long long bits = 0ull;
    if (i < NSEL) {
        float4 b = sbox[i];
        float ar = sarea[i];
        for (int j = 0; j < 64; ++j) {
            float xx1 = fmaxf(b.x, cb[j].x);
            float yy1 = fmaxf(b.y, cb[j].y);
            float xx2 = fminf(b.z, cb[j].z);
            float yy2 = fminf(b.w, cb[j].w);
            float w = fmaxf(1e-10f, __fsub_rn(xx2, xx1));
            float h = fmaxf(1e-10f, __fsub_rn(yy2, yy1));
            float inter = __fmul_rn(w, h);
            float denom = __fadd_rn(__fsub_rn(__fadd_rn(ar, ca[j]), inter), 1e-14f);
            float ovr = __fdiv_rn(inter, denom);
            if (ovr > 0.6f) bits |= (1ull << j);
        }
    }
    maskC[(size_t)colTile * NPAD + i] = bits;   // coalesced; pad rows get 0
}

// ---------- 5. greedy sweep: 16-wave incremental pipeline ----------
// wave k owns word-blocks b with b%16==k (<=5 each); per owned block a running
// suppression accumulator acc[j] lives in registers. Per step b:
//   owner wave: avail = ballot(acc==0) & valbits; branchless serial-64 readlane
//   sweep -> K; publish keptw[b] (LDS, double-buffered) ; ONE barrier;
//   all waves: acc[j] |= maskC[b][c_j] & keptw[b]  for owned blocks bj > b.
// maskC[b][*] loads are independent of keptw -> prefetched 2 steps ahead into
// static double-buffered registers (A/B), so the critical path per step is just
// sweep + barrier (~no memory latency).
__global__ __launch_bounds__(1024) void sweep_kernel(
        const unsigned long long* __restrict__ maskC,
        const int* __restrict__ order, const int* __restrict__ svalid,
        float* __restrict__ out_keep) {
    const int tid = threadIdx.x;
    const int lane = tid & 63;
    const int wave = tid >> 6;
    __shared__ unsigned long long kept_lds[2];

    unsigned long long acc[5] = {0ull, 0ull, 0ull, 0ull, 0ull};
    unsigned long long valw[5];
    int ordreg[5];
    #pragma unroll
    for (int j = 0; j < 5; ++j) {
        int bj = wave + 16 * j;
        int c = bj * 64 + lane;
        int v = 0, o = 0;
        if (bj < NWORDS && c < NSEL) { v = svalid[c]; o = order[c]; }
        valw[j] = __ballot(v != 0);
        ordreg[j] = o;
    }

    unsigned long long bufA[5], bufB[5];
    auto PF = [&](unsigned long long (&buf)[5], int b) {
        #pragma unroll
        for (int j = 0; j < 5; ++j) {
            int bj = wave + 16 * j;
            unsigned long long v = 0ull;
            if (b < NWORDS && bj < NWORDS && bj >= b)
                v = maskC[(size_t)b * NPAD + (size_t)(bj * 64 + lane)];
            buf[j] = v;
        }
    };
    auto STEP = [&](unsigned long long (&buf)[5], int b) {
        if (wave == (b & 15)) {
            unsigned long long diag = 0ull, myacc = 0ull, vb = 0ull; int myord = 0;
            #pragma unroll
            for (int j = 0; j < 5; ++j) {
                int bj = wave + 16 * j;
                if (bj == b) { diag = buf[j]; myacc = acc[j]; vb = valw[j]; myord = ordreg[j]; }
            }
            unsigned long long avail = __ballot(myacc == 0ull) & vb;
            unsigned long long K = 0ull;
            #pragma unroll
            for (int r = 0; r < 64; ++r) {
                unsigned int rl = __builtin_amdgcn_readlane((unsigned int)diag, r);
                unsigned int rh = __builtin_amdgcn_readlane((unsigned int)(diag >> 32), r);
                unsigned long long row = ((unsigned long long)rh << 32) | (unsigned long long)rl;
                unsigned long long bit = 1ull << r;
                bool take = (avail & bit) != 0ull;
                K     = take ? (K | bit)      : K;
                avail = take ? (avail & ~row) : avail;
            }
            if ((K >> lane) & 1ull) out_keep[myord] = 1.0f;
            if (lane == 0) kept_lds[b & 1] = K;
        }
        __syncthreads();
        unsigned long long kb = kept_lds[b & 1];
        #pragma unroll
        for (int j = 0; j < 5; ++j) {
            int bj = wave + 16 * j;
            if (bj < NWORDS && bj > b) acc[j] |= buf[j] & kb;
        }
    };

    PF(bufA, 0);
    PF(bufB, 1);
    int b = 0;
    for (; b + 1 < NWORDS; b += 2) {
        STEP(bufA, b);     PF(bufA, b + 2);
        STEP(bufB, b + 1); PF(bufB, b + 3);
    }
    if (b < NWORDS) STEP(bufA, b);   // NWORDS odd -> last block in A
}

// ---------- workspace layout (all 16B-aligned) ----------
constexpr size_t OFF_KEYS    = 0;                            // u64 * 87296
constexpr size_t OFF_SCORES  = OFF_KEYS    + 698368;         // f32 * 87296
constexpr size_t OFF_LABELS  = OFF_SCORES  + 349184;         // i32 * 87296
constexpr size_t OFF_BOXES   = OFF_LABELS  + 349184;         // f32x4 * 87296
constexpr size_t OFF_SEL     = OFF_BOXES   + 1396736;        // u64 * 4000
constexpr size_t OFF_ORDER   = OFF_SEL     + 32000;          // i32 * 4256
constexpr size_t OFF_SBOX    = OFF_ORDER   + 17024;          // f32x4 * 4256
constexpr size_t OFF_SAREA   = OFF_SBOX    + 68096;          // f32 * 4256
constexpr size_t OFF_SVALID  = OFF_SAREA   + 17024;          // i32 * 4256
constexpr size_t OFF_MASK    = OFF_SVALID  + 17024;          // u64 * NWORDS * NPAD

extern "C" void kernel_launch(void* const* d_in, const int* in_sizes, int n_in,
                              void* d_out, int out_size, void* d_ws, size_t ws_size,
                              hipStream_t stream) {
    (void)in_sizes; (void)n_in; (void)out_size; (void)ws_size;
    InPtrs P;
    for (int lv = 0; lv < 5; ++lv) {
        P.cls[lv] = (const float*)d_in[3 * lv + 0];
        P.reg[lv] = (const float*)d_in[3 * lv + 1];
        P.ctn[lv] = (const float*)d_in[3 * lv + 2];
    }
    P.scales = (const float*)d_in[15];

    char* ws = (char*)d_ws;
    unsigned long long* keys   = (unsigned long long*)(ws + OFF_KEYS);
    float*              scores = (float*)             (ws + OFF_SCORES);
    int*                labels = (int*)               (ws + OFF_LABELS);
    float4*             boxes  = (float4*)            (ws + OFF_BOXES);
    unsigned long long* sel    = (unsigned long long*)(ws + OFF_SEL);
    int*                order  = (int*)               (ws + OFF_ORDER);
    float4*             sbox   = (float4*)            (ws + OFF_SBOX);
    float*              sarea  = (float*)             (ws + OFF_SAREA);
    int*                svalid = (int*)               (ws + OFF_SVALID);
    unsigned long long* maskb  = (unsigned long long*)(ws + OFF_MASK);
    float* out = (float*)d_out;

    decode_kernel<<<TOTAL_ANCHORS / 256, 256, 0, stream>>>(P, keys, scores, labels, boxes);
    topk_kernel<<<4, 1024, 0, stream>>>(keys, sel);
    mid_kernel<<<1, 1024, 0, stream>>>(sel, scores, labels, boxes, out,
                                       order, sbox, sarea, svalid);
    mask_kernel<<<dim3(NWORDS, NWORDS), 64, 0, stream>>>(sbox, sarea, maskb);
    sweep_kernel<<<1, 1024, 0, stream>>>(maskb, order, svalid, out + 25536);
}

// Round 4
// 227.763 us; speedup vs baseline: 4.5783x; 1.9489x over previous
//
#include <hip/hip_runtime.h>
#include <math.h>

#define TOTAL_ANCHORS 87296
#define NSEL 4256
#define NWORDS 67          // ceil(4256/64)
#define NPAD   4288        // 67*64, padded row count for word-major mask
#define NREP 32            // histogram replicas
#define MAXROUNDS 4300     // safety cap; progress guarantee => <= NSEL rounds

// ---------- helpers ----------
__device__ __forceinline__ float sigmoidf_(float x) {
    return 1.0f / (1.0f + expf(-x));
}
// monotone float->uint mapping (ascending)
__device__ __forceinline__ unsigned int f2s(float f) {
    unsigned int u = __float_as_uint(f);
    return u ^ ((u >> 31) ? 0xFFFFFFFFu : 0x80000000u);
}

struct InPtrs {
    const float* cls[5];
    const float* reg[5];
    const float* ctn[5];
    const float* scales;
};

// ---------- 1. decode: per-anchor score/label/box + sort key ----------
__global__ __launch_bounds__(256) void decode_kernel(InPtrs in,
        unsigned long long* __restrict__ keys, float* __restrict__ scores,
        int* __restrict__ labels, float4* __restrict__ boxes) {
    int g = blockIdx.x * 256 + threadIdx.x;
    if (g >= TOTAL_ANCHORS) return;
    int lv, base, W, stride;
    if (g < 65536)      { lv = 0; base = 0;     W = 256; stride = 8;   }
    else if (g < 81920) { lv = 1; base = 65536; W = 128; stride = 16;  }
    else if (g < 86016) { lv = 2; base = 81920; W = 64;  stride = 32;  }
    else if (g < 87040) { lv = 3; base = 86016; W = 32;  stride = 64;  }
    else                { lv = 4; base = 87040; W = 16;  stride = 128; }
    int p = g - base;
    int HW = W * W;
    int x = p & (W - 1);
    int y = p / W;
    const float* cls = in.cls[lv];
    float sctn = sigmoidf_(in.ctn[lv][p]);
    float best = -1.0f; int lbl = 0;
    for (int c = 0; c < 80; ++c) {
        float v = cls[c * HW + p];
        float pr = sqrtf(__fmul_rn(sigmoidf_(v), sctn));
        if (pr > best) { best = pr; lbl = c; }   // strict > : first-index argmax
    }
    float scale = in.scales[lv];
    float fs = (float)stride;
    const float* rg = in.reg[lv];
    float r0 = __fmul_rn(fmaxf(__fmul_rn(rg[0 * HW + p], scale), 0.0f), fs);
    float r1 = __fmul_rn(fmaxf(__fmul_rn(rg[1 * HW + p], scale), 0.0f), fs);
    float r2 = __fmul_rn(fmaxf(__fmul_rn(rg[2 * HW + p], scale), 0.0f), fs);
    float r3 = __fmul_rn(fmaxf(__fmul_rn(rg[3 * HW + p], scale), 0.0f), fs);
    float ax = __fmul_rn(__fadd_rn((float)x, 0.5f), fs);
    float ay = __fmul_rn(__fadd_rn((float)y, 0.5f), fs);
    float4 b;
    b.x = __fsub_rn(ax, r0);
    b.y = __fsub_rn(ay, r1);
    b.z = __fadd_rn(ax, r2);
    b.w = __fadd_rn(ay, r3);
    scores[g] = best;
    labels[g] = lbl;
    boxes[g]  = b;
    // key: score desc, local index asc on ties (lax.top_k semantics)
    keys[g] = ((unsigned long long)f2s(best) << 32) | (unsigned int)(~(unsigned int)p);
}

// ---------- 2. per-level top-1000: radix-select with EARLY EXIT + bitonic ------
// Stop refining the radix prefix as soon as the candidate set (keys >= prefix
// at current shift) fits in 1024; bitonic-sort candidates (zero-padded) and
// take the top 1000. Keys are unique, so selection is exact.
__global__ __launch_bounds__(1024) void topk_kernel(
        const unsigned long long* __restrict__ keys,
        unsigned long long* __restrict__ sel) {
    __shared__ unsigned int hist[256][NREP];
    __shared__ unsigned int histm[256];
    __shared__ unsigned long long sh_prefix;
    __shared__ int sh_need, sh_total;
    __shared__ unsigned long long skeys[1024];
    __shared__ int cnt;
    const int level = blockIdx.x;
    const int Ns_[4]   = {65536, 16384, 4096, 1024};
    const int offs_[4] = {0, 65536, 81920, 86016};
    const int N = Ns_[level];
    const unsigned long long* kbase = keys + offs_[level];
    const int tid = threadIdx.x;
    const int rep = tid & (NREP - 1);
    unsigned long long prefix = 0ull;
    int need = 1000;
    int sel_shift = 0;
    for (int bp = 7; bp >= 0; --bp) {
        for (int i = tid; i < 256 * NREP; i += 1024) ((unsigned int*)hist)[i] = 0u;
        __syncthreads();
        const int shift = bp * 8;
        for (int i = tid; i < N; i += 1024) {
            unsigned long long k = kbase[i];
            unsigned long long hi = k >> shift;
            if ((hi >> 8) == prefix) atomicAdd(&hist[(int)(hi & 255ull)][rep], 1u);
        }
        __syncthreads();
        if (tid < 256) {
            unsigned int s = 0;
            #pragma unroll
            for (int r2 = 0; r2 < NREP; ++r2) s += hist[tid][(r2 + tid) & (NREP - 1)];
            histm[tid] = s;
        }
        __syncthreads();
        if (tid == 0) {
            int c = 0, b = 255;
            for (; b >= 0; --b) { int h = (int)histm[b]; if (c + h >= need) break; c += h; }
            if (b < 0) b = 0;
            sh_prefix = (prefix << 8) | (unsigned long long)(unsigned int)b;
            sh_need = need - c;
            sh_total = (1000 - need) + c + (int)histm[b];  // |{k : k>>shift >= newprefix}|
        }
        __syncthreads();
        prefix = sh_prefix;
        need = sh_need;
        int total = sh_total;
        __syncthreads();
        if (total <= 1024) { sel_shift = shift; break; }   // candidates fit -> stop
        // (if loop runs to bp==0, sel_shift stays 0 and |candidates| == 1000)
    }
    if (tid == 0) cnt = 0;
    skeys[tid] = 0ull;
    __syncthreads();
    for (int i = tid; i < N; i += 1024) {
        unsigned long long k = kbase[i];
        if ((k >> sel_shift) >= prefix) { int p = atomicAdd(&cnt, 1); if (p < 1024) skeys[p] = k; }
    }
    __syncthreads();
    // bitonic sort 1024 descending (zero pads sink: real keys have f2s>=0x80000000)
    for (int kk = 2; kk <= 1024; kk <<= 1) {
        for (int j = kk >> 1; j > 0; j >>= 1) {
            int ixj = tid ^ j;
            if (ixj > tid) {
                unsigned long long a = skeys[tid], b2 = skeys[ixj];
                bool sw = ((tid & kk) == 0) ? (a < b2) : (a > b2);
                if (sw) { skeys[tid] = b2; skeys[ixj] = a; }
            }
            __syncthreads();
        }
    }
    if (tid < 1000) sel[level * 1000 + tid] = skeys[tid];
}

// ---------- 3. fused mid: finalize + sort-l4 + merge-rank (one block, 1024 thr) ----
__device__ __forceinline__ int count_greater(const unsigned long long* A, int n,
                                             unsigned long long x) {
    int lo = 0, hi = n;
    while (lo < hi) { int m = (lo + hi) >> 1; if (A[m] > x) lo = m + 1; else hi = m; }
    return lo;
}
__global__ __launch_bounds__(1024) void mid_kernel(
        const unsigned long long* __restrict__ sel,
        const float* __restrict__ scores, const int* __restrict__ labels,
        const float4* __restrict__ boxes, float* __restrict__ out,
        int* __restrict__ order, float4* __restrict__ sbox,
        float* __restrict__ sarea, int* __restrict__ svalid) {
    __shared__ unsigned long long ekey[NSEL];
    __shared__ unsigned long long sk4[256];
    const int tid = threadIdx.x;
    float4 bxs[5]; float ars[5]; int vls[5];
    // ---- phase 1: finalize (gather top-k, write outputs, build NMS entries) ----
    #pragma unroll
    for (int k = 0; k < 5; ++k) {
        int pos = tid + k * 1024;
        if (pos < NSEL) {
            int g;
            if (pos < 4000) {
                int lv = pos / 1000;
                const int offs_[4] = {0, 65536, 81920, 86016};
                unsigned long long key = sel[pos];
                unsigned int p = ~((unsigned int)(key & 0xFFFFFFFFull));
                g = offs_[lv] + (int)p;
            } else {
                g = 87040 + (pos - 4000);   // level 4: raw order
            }
            float sc = scores[g];
            int lb = labels[g];
            float4 bx = boxes[g];
            const float inv = 1.0f / 2048.0f;   // /2048 == *2^-11 exactly
            out[pos * 4 + 0] = fminf(fmaxf(__fmul_rn(bx.x, inv), 0.0f), 1.0f);
            out[pos * 4 + 1] = fminf(fmaxf(__fmul_rn(bx.y, inv), 0.0f), 1.0f);
            out[pos * 4 + 2] = fminf(fmaxf(__fmul_rn(bx.z, inv), 0.0f), 1.0f);
            out[pos * 4 + 3] = fminf(fmaxf(__fmul_rn(bx.w, inv), 0.0f), 1.0f);
            out[17024 + pos] = sc;
            out[21280 + pos] = (float)lb;
            out[25536 + pos] = 0.0f;            // keep default; sweep sets kept=1
            float off = __fmul_rn((float)lb, 100000.0f);
            float4 eb;
            eb.x = __fadd_rn(bx.x, off); eb.y = __fadd_rn(bx.y, off);
            eb.z = __fadd_rn(bx.z, off); eb.w = __fadd_rn(bx.w, off);
            bxs[k] = eb;
            ars[k] = __fmul_rn(__fsub_rn(eb.z, eb.x), __fsub_rn(eb.w, eb.y));
            int valid = (sc >= 0.05f) ? 1 : 0;
            vls[k] = valid;
            float effs = valid ? sc : -INFINITY;
            ekey[pos] = ((unsigned long long)f2s(effs) << 32) | (unsigned int)(~(unsigned int)pos);
        }
    }
    __syncthreads();
    // ---- phase 2: bitonic-sort the 256 level-4 keys (only unsorted chunk) ----
    if (tid < 256) sk4[tid] = ekey[4000 + tid];
    __syncthreads();
    for (int kk = 2; kk <= 256; kk <<= 1) {
        for (int j = kk >> 1; j > 0; j >>= 1) {
            if (tid < 256) {
                int ixj = tid ^ j;
                if (ixj > tid) {
                    unsigned long long a = sk4[tid], b = sk4[ixj];
                    bool sw = ((tid & kk) == 0) ? (a < b) : (a > b);
                    if (sw) { sk4[tid] = b; sk4[ixj] = a; }
                }
            }
            __syncthreads();
        }
    }
    // ---- phase 3: merge-rank (stable global sort via binary-search ranks) ----
    #pragma unroll
    for (int k = 0; k < 5; ++k) {
        int pos = tid + k * 1024;
        if (pos < NSEL) {
            unsigned long long x = ekey[pos];
            int rank = count_greater(ekey,        1000, x)
                     + count_greater(ekey + 1000, 1000, x)
                     + count_greater(ekey + 2000, 1000, x)
                     + count_greater(ekey + 3000, 1000, x)
                     + count_greater(sk4,          256, x);
            order[rank]  = pos;
            sbox[rank]   = bxs[k];
            sarea[rank]  = ars[k];
            svalid[rank] = vls[k];
        }
    }
}

// ---------- 4. IoU bitmask, WORD-MAJOR layout: maskC[w*NPAD + row] ----------
// Only lower-triangle word tiles (colTile <= rowTile) are ever read by the sweep.
__global__ __launch_bounds__(64) void mask_kernel(
        const float4* __restrict__ sbox, const float* __restrict__ sarea,
        unsigned long long* __restrict__ maskC) {
    int colTile = blockIdx.x, rowTile = blockIdx.y;
    if (colTile > rowTile) return;
    __shared__ float4 cb[64];
    __shared__ float ca[64];
    int tid = threadIdx.x;
    int col0 = colTile * 64;
    int c = col0 + tid;
    if (c < NSEL) { cb[tid] = sbox[c]; ca[tid] = sarea[c]; }
    else { cb[tid] = make_float4(0.f, 0.f, 0.f, 0.f); ca[tid] = 0.f; }
    __syncthreads();
    int i = rowTile * 64 + tid;
    unsigned long long bits = 0ull;
    if (i < NSEL) {
        float4 b = sbox[i];
        float ar = sarea[i];
        for (int j = 0; j < 64; ++j) {
            float xx1 = fmaxf(b.x, cb[j].x);
            float yy1 = fmaxf(b.y, cb[j].y);
            float xx2 = fminf(b.z, cb[j].z);
            float yy2 = fminf(b.w, cb[j].w);
            float w = fmaxf(1e-10f, __fsub_rn(xx2, xx1));
            float h = fmaxf(1e-10f, __fsub_rn(yy2, yy1));
            float inter = __fmul_rn(w, h);
            float denom = __fadd_rn(__fsub_rn(__fadd_rn(ar, ca[j]), inter), 1e-14f);
            float ovr = __fdiv_rn(inter, denom);
            if (ovr > 0.6f) bits |= (1ull << j);
        }
        // garbage bits vs pad columns never matter: pad boxes are never unk/kept
    }
    maskC[(size_t)colTile * NPAD + i] = bits;   // coalesced; pad rows store 0
}

// ---------- 5. greedy sweep as PARALLEL FIXED-POINT (no serial 67-step chain) --
// Greedy keep is the unique fixed point of:
//   UNKNOWN c:  accK = OR_{j<c} m[j][c]&kept[j],  accU = OR_{j<c} m[j][c]&unk[j]
//   accK!=0           -> REMOVED (final)
//   accK==0 && accU==0 -> KEPT   (final)
// The earliest undecided box always decides each round => termination; rounds ~=
// longest suppression chain (~2-5 for this data). Round 1 is a fully parallel
// triangular bitmask matvec (TLP across 16 waves, coalesced loads); later
// rounds touch only undecided columns. 2 barriers/round, word commits via ballot.
__global__ __launch_bounds__(1024) void sweep_kernel(
        const unsigned long long* __restrict__ maskC,
        const int* __restrict__ order, const int* __restrict__ svalid,
        float* __restrict__ out_keep) {
    const int tid = threadIdx.x;
    const int lane = tid & 63;
    const int wave = tid >> 6;
    __shared__ unsigned long long keptL[NWORDS], unkL[NWORDS];
    __shared__ unsigned long long nk[NWORDS], nd[NWORDS];
    __shared__ int wflag[16];

    #pragma unroll
    for (int k = 0; k < 5; ++k) {
        int b = wave + 16 * k;
        if (b >= NWORDS) continue;
        int c = b * 64 + lane;
        int v = (c < NSEL) ? svalid[c] : 0;
        unsigned long long w = __ballot(v != 0);
        if (lane == 0) { unkL[b] = w; keptL[b] = 0ull; }
    }
    __syncthreads();

    for (int round = 0; round < MAXROUNDS; ++round) {
        // ---- compute phase (reads keptL/unkL snapshot, writes nk/nd) ----
        #pragma unroll
        for (int k = 0; k < 5; ++k) {
            int b = wave + 16 * k;
            if (b >= NWORDS) continue;
            int c = b * 64 + lane;
            unsigned long long uw = unkL[b];
            bool dec = false, kp = false;
            if (uw) {                              // wave-uniform skip
                bool myunk = (uw >> lane) & 1ull;
                if (myunk) {
                    unsigned long long accK = 0ull, accU = 0ull;
                    #pragma unroll 4
                    for (int w = 0; w < b; ++w) {
                        unsigned long long kw = keptL[w], uw2 = unkL[w];
                        if (kw | uw2) {            // wave-uniform skip of dead words
                            unsigned long long m = maskC[(size_t)w * NPAD + c];
                            accK |= m & kw;
                            accU |= m & uw2;
                        }
                    }
                    unsigned long long below = (1ull << lane) - 1ull;
                    unsigned long long md = maskC[(size_t)b * NPAD + c];
                    accK |= md & keptL[b] & below;
                    accU |= md & uw & below;
                    if (accK) { dec = true; }
                    else if (accU == 0ull) { dec = true; kp = true; }
                }
            }
            unsigned long long kb = __ballot(kp);
            unsigned long long db = __ballot(dec);
            if (lane == 0) { nk[b] = kb; nd[b] = db; }
        }
        __syncthreads();
        // ---- commit phase ----
        int any = 0;
        #pragma unroll
        for (int k = 0; k < 5; ++k) {
            int b = wave + 16 * k;
            if (b >= NWORDS) continue;
            unsigned long long db = nd[b];
            if (lane == 0) {
                keptL[b] |= nk[b];
                unkL[b]  &= ~db;
            }
            any |= (db != 0ull) ? 1 : 0;
        }
        if (lane == 0) wflag[wave] = any;
        __syncthreads();
        int anych = 0;
        #pragma unroll
        for (int w = 0; w < 16; ++w) anych |= wflag[w];
        if (!anych) break;
    }

    // ---- write kept flags ----
    #pragma unroll
    for (int k = 0; k < 5; ++k) {
        int b = wave + 16 * k;
        if (b >= NWORDS) continue;
        int c = b * 64 + lane;
        if (c < NSEL && ((keptL[b] >> lane) & 1ull)) out_keep[order[c]] = 1.0f;
    }
}

// ---------- workspace layout (all 16B-aligned) ----------
constexpr size_t OFF_KEYS    = 0;                            // u64 * 87296
constexpr size_t OFF_SCORES  = OFF_KEYS    + 698368;         // f32 * 87296
constexpr size_t OFF_LABELS  = OFF_SCORES  + 349184;         // i32 * 87296
constexpr size_t OFF_BOXES   = OFF_LABELS  + 349184;         // f32x4 * 87296
constexpr size_t OFF_SEL     = OFF_BOXES   + 1396736;        // u64 * 4000
constexpr size_t OFF_ORDER   = OFF_SEL     + 32000;          // i32 * 4256
constexpr size_t OFF_SBOX    = OFF_ORDER   + 17024;          // f32x4 * 4256
constexpr size_t OFF_SAREA   = OFF_SBOX    + 68096;          // f32 * 4256
constexpr size_t OFF_SVALID  = OFF_SAREA   + 17024;          // i32 * 4256
constexpr size_t OFF_MASK    = OFF_SVALID  + 17024;          // u64 * NWORDS * NPAD

extern "C" void kernel_launch(void* const* d_in, const int* in_sizes, int n_in,
                              void* d_out, int out_size, void* d_ws, size_t ws_size,
                              hipStream_t stream) {
    (void)in_sizes; (void)n_in; (void)out_size; (void)ws_size;
    InPtrs P;
    for (int lv = 0; lv < 5; ++lv) {
        P.cls[lv] = (const float*)d_in[3 * lv + 0];
        P.reg[lv] = (const float*)d_in[3 * lv + 1];
        P.ctn[lv] = (const float*)d_in[3 * lv + 2];
    }
    P.scales = (const float*)d_in[15];

    char* ws = (char*)d_ws;
    unsigned long long* keys   = (unsigned long long*)(ws + OFF_KEYS);
    float*              scores = (float*)             (ws + OFF_SCORES);
    int*                labels = (int*)               (ws + OFF_LABELS);
    float4*             boxes  = (float4*)            (ws + OFF_BOXES);
    unsigned long long* sel    = (unsigned long long*)(ws + OFF_SEL);
    int*                order  = (int*)               (ws + OFF_ORDER);
    float4*             sbox   = (float4*)            (ws + OFF_SBOX);
    float*              sarea  = (float*)             (ws + OFF_SAREA);
    int*                svalid = (int*)               (ws + OFF_SVALID);
    unsigned long long* maskb  = (unsigned long long*)(ws + OFF_MASK);
    float* out = (float*)d_out;

    decode_kernel<<<TOTAL_ANCHORS / 256, 256, 0, stream>>>(P, keys, scores, labels, boxes);
    topk_kernel<<<4, 1024, 0, stream>>>(keys, sel);
    mid_kernel<<<1, 1024, 0, stream>>>(sel, scores, labels, boxes, out,
                                       order, sbox, sarea, svalid);
    mask_kernel<<<dim3(NWORDS, NWORDS), 64, 0, stream>>>(sbox, sarea, maskb);
    sweep_kernel<<<1, 1024, 0, stream>>>(maskb, order, svalid, out + 25536);
}